// Round 20
// baseline (304.100 us; speedup 1.0000x reference)
//
#include <hip/hip_runtime.h>
#include <stdint.h>

#define B_DIM 8192
#define DIN   2048
#define DOUT  8192
#define NKT   (DIN / 128)  // 16 K-tiles of 128 bytes

typedef int  v4i __attribute__((ext_vector_type(4)));
typedef char c8  __attribute__((ext_vector_type(8)));

__device__ __forceinline__ void gload_lds16(const void* g, void* l) {
  __builtin_amdgcn_global_load_lds(
      (const __attribute__((address_space(1))) void*)g,
      (__attribute__((address_space(3))) void*)l, 16, 0, 0);
}

__device__ __forceinline__ float wave_max(float m) {
#pragma unroll
  for (int off = 32; off; off >>= 1) m = fmaxf(m, __shfl_xor(m, off, 64));
  return m;
}

// ---- kernel 0: zero the two atomic absmax words ----
__global__ void k_init(unsigned int* p) {
  p[0] = 0u;
  p[1] = 0u;
}

// ---- kernel 1: global absmax of x (block-reduced, 1 atomic/block) ----
__global__ __launch_bounds__(256) void k_absmax(const float4* __restrict__ x,
                                                int n4,
                                                unsigned int* __restrict__ out_bits) {
  int idx = blockIdx.x * blockDim.x + threadIdx.x;
  int stride = gridDim.x * blockDim.x;
  float m = 0.f;
  for (int i = idx; i < n4; i += stride) {
    float4 v = x[i];
    m = fmaxf(m, fabsf(v.x));
    m = fmaxf(m, fabsf(v.y));
    m = fmaxf(m, fabsf(v.z));
    m = fmaxf(m, fabsf(v.w));
  }
  m = wave_max(m);
  __shared__ float red[4];
  if ((threadIdx.x & 63) == 0) red[threadIdx.x >> 6] = m;
  __syncthreads();
  if (threadIdx.x == 0) {
    m = fmaxf(fmaxf(red[0], red[1]), fmaxf(red[2], red[3]));
    atomicMax(out_bits, __float_as_uint(m));
  }
}

// ---- kernel 2: quantize x to int8 (8 elems/thread) ----
__global__ void k_quant_x(const float* __restrict__ x, c8* __restrict__ xq,
                          int n8, const unsigned int* __restrict__ sa_bits) {
  int i = blockIdx.x * blockDim.x + threadIdx.x;
  if (i >= n8) return;
  float s_a = __uint_as_float(*sa_bits) / 127.0f;
  const float4* p = (const float4*)(x + (size_t)i * 8);
  float4 v0 = p[0], v1 = p[1];
  float vv[8] = {v0.x, v0.y, v0.z, v0.w, v1.x, v1.y, v1.z, v1.w};
  c8 q;
#pragma unroll
  for (int j = 0; j < 8; ++j) {
    float r = fminf(fmaxf(rintf(vv[j] / s_a), -127.f), 127.f);
    q[j] = (char)(int)r;
  }
  xq[i] = q;
}

// ---- kernel 3: per-row weight absmax + quantize (1 block / row) ----
__global__ __launch_bounds__(256) void k_quant_w(const float* __restrict__ w,
                                                 c8* __restrict__ wq,
                                                 float* __restrict__ s_w) {
  int row = blockIdx.x;
  int tid = threadIdx.x;
  const float4* wr = (const float4*)(w + (size_t)row * DIN);
  float4 v0 = wr[tid * 2], v1 = wr[tid * 2 + 1];
  float vv[8] = {v0.x, v0.y, v0.z, v0.w, v1.x, v1.y, v1.z, v1.w};
  float m = 0.f;
#pragma unroll
  for (int j = 0; j < 8; ++j) m = fmaxf(m, fabsf(vv[j]));
  m = wave_max(m);
  __shared__ float wmax[4];
  if ((tid & 63) == 0) wmax[tid >> 6] = m;
  __syncthreads();
  m = fmaxf(fmaxf(wmax[0], wmax[1]), fmaxf(wmax[2], wmax[3]));
  float s = m / 127.0f;
  if (tid == 0) s_w[row] = s;
  c8 q;
#pragma unroll
  for (int j = 0; j < 8; ++j) {
    float r = fminf(fmaxf(rintf(vv[j] / s), -127.f), 127.f);
    q[j] = (char)(int)r;
  }
  wq[(size_t)row * (DIN / 8) + tid] = q;
}

// ---- kernel 4: int8 GEMM 256x256, full-line staging, 2-PHASE DMA PIPELINE -
// R18 champion, verbatim (passed, 153us GEMM / 303.6us total, MfmaUtil 39.5%).
// R19's vmcnt(6) variant RACED: a wave's vmcnt wait confirms only ITS OWN
// DMA issues; cross-wave safety requires confirm-wait -> BARRIER -> read.
// vmcnt(4) here: A units staged at q-3 are confirmed at wait@(q-1), barrier
// at end of (q-1), read at q -- safe for all waves. B units lead >=4.
// Memory map: LDS row-major [256][128B]/operand/slot, 16B-slot XOR swizzle
// (slot^=row&7); pre-swizzled SOURCE + swizzled READ (rule #21); full
// 128B-line DMA sources (8 rows x 128B per gload instruction).
// Units: (op, quarter q=64 rows) = 8KB = 1 gload/thread.
// Calendar (tau = current tile; stages issued at PHASE TOP, before reads):
//   p1: B q2,q3(tau+1)   p2: A q0,q2(tau+1)   p3: A q1,q3(tau+1)
//   p4: B q0,q1(tau+2)
// WAR audit: every restage >=1 barrier after its region's last read.
// Tails: kt>=NKT -> NKT-2+(kt&1): same slot, identical bytes (idempotent).
__global__ __launch_bounds__(512) void k_gemm8(
    const char* __restrict__ Aq, const char* __restrict__ Bq,
    const float* __restrict__ s_w, const float* __restrict__ bias,
    const unsigned int* __restrict__ sa_bits, float* __restrict__ out,
    unsigned int* __restrict__ omax_bits) {
  __shared__ __align__(16) char lds[131072];

  const int tid = threadIdx.x;
  const int lane = tid & 63;
  const int wave = tid >> 6;
  const int wm = wave >> 2;  // 0..1 (M)
  const int wn = wave & 3;   // 0..3 (N)

  // bijective 2D L2-patch swizzle (R4-verified: FETCH 271->99 MB)
  const int orig = blockIdx.x;
  const int xcd = orig & 7;
  const int k = orig >> 3;
  const int bx = (xcd & 3) * 8 + (k & 7);
  const int by = (xcd >> 2) * 16 + (k >> 3);
  const int row0 = by * 256, col0 = bx * 256;

  // staging: thread t covers row_local = t>>3 (64 rows/gload), 16B slot t&7;
  // source slot pre-swizzled: global kbyte = 16*((t&7)^((t>>3)&7)).
  const size_t srcOff =
      (size_t)(tid >> 3) * DIN + 16 * ((tid & 7) ^ ((tid >> 3) & 7));
  const char* aS = Aq + (size_t)row0 * DIN + srcOff;
  const char* bS = Bq + (size_t)col0 * DIN + srcOff;

  // stage one (op, quarter) unit of K-tile kt (1 gload, 8KB)
  auto STAGE1 = [&](int kt, int isB, int q) {
    if (kt >= NKT) kt = NKT - 2 + (kt & 1);  // tail: last same-parity tile
    const int slot = kt & 1;
    const char* src = (isB ? bS : aS) + (size_t)(q * 64) * DIN + (size_t)kt * 128;
    gload_lds16(src, &lds[slot * 65536 + isB * 32768 + q * 8192 + tid * 16]);
  };

  v4i acc[2][4][4];
#pragma unroll
  for (int mh = 0; mh < 2; ++mh)
#pragma unroll
    for (int mf = 0; mf < 4; ++mf)
#pragma unroll
      for (int nf = 0; nf < 4; ++nf) acc[mh][mf][nf] = (v4i){0, 0, 0, 0};

  const int fr = lane & 15;
  const int kg = lane >> 4;
  // swizzled lane part (ks=0): row-in-frag byte + 16*(kg ^ (fr&7)).
  // ks=1 flips bit 6 (slot^4): addr ^ 64.
  const int lp = fr * 128 + 16 * (kg ^ (fr & 7));
  v4i b_[4];  // persists across the (mh0, mh1) phase pair

#define PH(SLOT, KS, MH, SKT, SISB, SQA, SQB)                                \
  do {                                                                       \
    STAGE1(SKT, SISB, SQA);                                                  \
    STAGE1(SKT, SISB, SQB);                                                  \
    v4i a_[4];                                                               \
    const int ab = (SLOT) * 65536 + wm * 16384 + (MH) * 8192 + lp;           \
    const int bb = (SLOT) * 65536 + 32768 + wn * 8192 + lp;                  \
    if (!(MH)) b_[0] = *(const v4i*)&lds[bb ^ ((KS) * 64)];                  \
    _Pragma("unroll") for (int mf = 0; mf < 4; ++mf) a_[mf] =                \
        *(const v4i*)&lds[(ab + mf * 2048) ^ ((KS) * 64)];                   \
    if (!(MH)) {                                                             \
      _Pragma("unroll") for (int nf = 1; nf < 4; ++nf) b_[nf] =              \
          *(const v4i*)&lds[(bb + nf * 2048) ^ ((KS) * 64)];                 \
    }                                                                        \
    asm volatile("s_waitcnt vmcnt(4)" ::: "memory");                         \
    _Pragma("unroll") for (int nf = 0; nf < 4; ++nf)                         \
        _Pragma("unroll") for (int mf = 0; mf < 4; ++mf) acc[MH][mf][nf] =   \
        __builtin_amdgcn_mfma_i32_16x16x64_i8(a_[mf], b_[nf],                \
                                              acc[MH][mf][nf], 0, 0, 0);     \
    __builtin_amdgcn_s_barrier();                                            \
  } while (0)

  // prologue: tile0 fully (8 units) + tile1's B q0,q1 (the unit pair that
  // steady-state would have staged at (-1,p4)). vmcnt(2) confirms exactly
  // tile0's 8; tile1's pair stays in flight (confirmed by (0,p2)'s wait).
  STAGE1(0, 0, 0);
  STAGE1(0, 0, 2);
  STAGE1(0, 0, 1);
  STAGE1(0, 0, 3);
  STAGE1(0, 1, 0);
  STAGE1(0, 1, 1);
  STAGE1(0, 1, 2);
  STAGE1(0, 1, 3);
  STAGE1(1, 1, 0);
  STAGE1(1, 1, 1);
  asm volatile("s_waitcnt vmcnt(2)" ::: "memory");
  __builtin_amdgcn_s_barrier();

#pragma unroll 1
  for (int i = 0; i < NKT / 2; ++i) {
    const int t1 = 2 * i + 1, t2 = 2 * i + 2, t3 = 2 * i + 3;
    // tile 2i (slot 0)
    PH(0, 0, 0, t1, 1, 2, 3);  // p1: B q2,q3 (t1)
    PH(0, 0, 1, t1, 0, 0, 2);  // p2: A q0,q2 (t1)
    PH(0, 1, 0, t1, 0, 1, 3);  // p3: A q1,q3 (t1)
    PH(0, 1, 1, t2, 1, 0, 1);  // p4: B q0,q1 (t2)
    // tile 2i+1 (slot 1)
    PH(1, 0, 0, t2, 1, 2, 3);  // p1': B q2,q3 (t2)
    PH(1, 0, 1, t2, 0, 0, 2);  // p2': A q0,q2 (t2)
    PH(1, 1, 0, t2, 0, 1, 3);  // p3': A q1,q3 (t2)
    PH(1, 1, 1, t3, 1, 0, 1);  // p4': B q0,q1 (t3)
  }
#undef PH

  // epilogue: out = (acc + round(bias/s_b)) * s_b, s_b = s_w[col]*s_a
  float s_a = __uint_as_float(*sa_bits) / 127.0f;
  float lmax = 0.f;
#pragma unroll
  for (int nf = 0; nf < 4; ++nf) {
    int col = col0 + wn * 64 + nf * 16 + fr;
    float sw = s_w[col];
    float sb = sw * s_a;
    float bint = rintf(bias[col] / sb);
#pragma unroll
    for (int mh = 0; mh < 2; ++mh)
#pragma unroll
      for (int mf = 0; mf < 4; ++mf) {
        int rbase = row0 + wm * 128 + mh * 64 + mf * 16 + (lane >> 4) * 4;
#pragma unroll
        for (int r = 0; r < 4; ++r) {
          float o = ((float)acc[mh][mf][nf][r] + bint) * sb;
          out[(size_t)(rbase + r) * DOUT + col] = o;
          lmax = fmaxf(lmax, fabsf(o));
        }
      }
  }
  // block-level max reduce -> 1 atomic per block
  lmax = wave_max(lmax);
  asm volatile("s_waitcnt vmcnt(0)" ::: "memory");  // drain tail DMA into LDS
  __syncthreads();
  float* red = (float*)lds;
  if (lane == 0) red[wave] = lmax;
  __syncthreads();
  if (tid == 0) {
    float m = 0.f;
#pragma unroll
    for (int w2 = 0; w2 < 8; ++w2) m = fmaxf(m, red[w2]);
    atomicMax(omax_bits, __float_as_uint(m));
  }
}

// ---- kernel 5: requantize output in place ----
__global__ void k_requant(float4* __restrict__ out, int n4,
                          const unsigned int* __restrict__ omax_bits) {
  float s_o = __uint_as_float(*omax_bits) / 127.0f;
  int idx = blockIdx.x * blockDim.x + threadIdx.x;
  int stride = gridDim.x * blockDim.x;
  for (int i = idx; i < n4; i += stride) {
    float4 v = out[i];
    v.x = fminf(fmaxf(rintf(v.x / s_o), -127.f), 127.f) * s_o;
    v.y = fminf(fmaxf(rintf(v.y / s_o), -127.f), 127.f) * s_o;
    v.z = fminf(fmaxf(rintf(v.z / s_o), -127.f), 127.f) * s_o;
    v.w = fminf(fmaxf(rintf(v.w / s_o), -127.f), 127.f) * s_o;
    out[i] = v;
  }
}

extern "C" void kernel_launch(void* const* d_in, const int* in_sizes, int n_in,
                              void* d_out, int out_size, void* d_ws,
                              size_t ws_size, hipStream_t stream) {
  const float* x = (const float*)d_in[0];
  const float* w = (const float*)d_in[1];
  const float* bias = (const float*)d_in[2];
  float* out = (float*)d_out;
  char* ws = (char*)d_ws;

  unsigned int* absbits = (unsigned int*)ws;
  float* s_w = (float*)(ws + 512);
  char* xq = ws + 65536;
  char* wq = ws + 65536 + (size_t)B_DIM * DIN;

  k_init<<<1, 1, 0, stream>>>(absbits);
  k_absmax<<<1024, 256, 0, stream>>>((const float4*)x, B_DIM * DIN / 4, absbits);
  k_quant_x<<<(B_DIM * DIN / 8) / 256, 256, 0, stream>>>(x, (c8*)xq,
                                                         B_DIM * DIN / 8, absbits);
  k_quant_w<<<DOUT, 256, 0, stream>>>(w, (c8*)wq, s_w);
  k_gemm8<<<1024, 512, 0, stream>>>(xq, wq, s_w, bias, absbits, out, absbits + 1);
  k_requant<<<4096, 256, 0, stream>>>((float4*)out, B_DIM * DOUT / 4, absbits + 1);
}